// Round 6
// baseline (425.820 us; speedup 1.0000x reference)
//
#include <hip/hip_runtime.h>

// SENet layer, fp32 NHWC. B=32, H=W=56 (HW=3136), C=256, C/R=16.
// Single kernel, manual grid barrier (NO cooperative API — it failed to launch
// under the harness). GRID=784 blocks x 256 thr, __launch_bounds__(256,4)
// => VGPR<=128 => 4 blocks/CU => 1024 slots >= 784: all blocks co-resident,
// so the barrier cannot starve. Barrier atomics are agent-scope acq/rel
// (emits L2 wb/inv for cross-XCD visibility of partial[] and g[]).
//   phase 1: pool 2 tiles/block -> partial[1568][256]
//   barrier; blocks 0..31: reduce + MLP -> g[32][256]; barrier
//   phase 3: out = x * g (x LLC-hot from phase 1; nontemporal store)

#define BATCH 32
#define HW 3136
#define C 256
#define CR 16
#define SBLK 49              // 64-row tiles per batch
#define NTILE (BATCH * SBLK) // 1568
#define VPR 64               // float4 vectors per row
#define GRID 784             // 2 tiles per block

typedef float v4f __attribute__((ext_vector_type(4)));

__device__ __forceinline__ void grid_barrier(int* ctr, int target) {
    __syncthreads();                       // all block stores drained (vmcnt)
    if (threadIdx.x == 0) {
        __hip_atomic_fetch_add(ctr, 1, __ATOMIC_RELEASE, __HIP_MEMORY_SCOPE_AGENT);
        int spins = 0;
        while (__hip_atomic_load(ctr, __ATOMIC_ACQUIRE, __HIP_MEMORY_SCOPE_AGENT) < target) {
            __builtin_amdgcn_s_sleep(1);
            if (++spins > (1 << 20)) break;   // watchdog: fail loud, never hang
        }
    }
    __syncthreads();
}

__global__ __launch_bounds__(256, 4) void se_fused(
        const float* __restrict__ x,
        const float* __restrict__ w1, const float* __restrict__ b1,
        const float* __restrict__ w2, const float* __restrict__ b2,
        float* __restrict__ out,
        float* __restrict__ partial,   // ws: [NTILE][C]
        float* __restrict__ g,         // ws: [BATCH][C]
        int* __restrict__ sync) {      // ws: 2 counters, 128B apart, zeroed
    const int tid = threadIdx.x;
    const int bid = blockIdx.x;

    __shared__ float red[256 * 4];
    __shared__ float s2[C];
    __shared__ float h[CR];

    const v4f* __restrict__ xv = (const v4f*)x;

    // ---------------- phase 1: pooling partials, 2 tiles/block --------------
#pragma unroll
    for (int rep = 0; rep < 2; ++rep) {
        const int t    = bid + rep * GRID;
        const int lane = tid & 63;           // float4 index within a row
        const int rg   = tid >> 6;           // row group (0..3)
        const size_t vbase = (size_t)t * 4096;   // 64 rows * 64 vec/row

        v4f a = (v4f)(0.f);
#pragma unroll
        for (int k = 0; k < 16; ++k)
            a += xv[vbase + (size_t)(rg + 4 * k) * VPR + lane];

        red[tid * 4 + 0] = a.x;
        red[tid * 4 + 1] = a.y;
        red[tid * 4 + 2] = a.z;
        red[tid * 4 + 3] = a.w;
        __syncthreads();

        if (tid < 64) {
#pragma unroll
            for (int q = 1; q < 4; ++q) {
                a.x += red[(q * 64 + tid) * 4 + 0];
                a.y += red[(q * 64 + tid) * 4 + 1];
                a.z += red[(q * 64 + tid) * 4 + 2];
                a.w += red[(q * 64 + tid) * 4 + 3];
            }
            float* dst = partial + (size_t)t * C + tid * 4;
            dst[0] = a.x; dst[1] = a.y; dst[2] = a.z; dst[3] = a.w;
        }
        __syncthreads();   // red reused
    }

    grid_barrier(sync, GRID);

    // ---------------- phase 2: MLP, blocks 0..31 ----------------------------
    if (bid < BATCH) {
        const int b = bid;
        {
            float sum = 0.f;
            const float* pb = partial + (size_t)b * SBLK * C + tid;
#pragma unroll 7
            for (int k = 0; k < SBLK; ++k) sum += pb[k * C];
            s2[tid] = sum * (1.0f / (float)HW);
        }
        __syncthreads();

        // layer 1: 16 outputs x 16 reduction lanes; w1 reads coalesced
        {
            const int j = tid & 15;
            const int i = tid >> 4;
            float a = 0.f;
#pragma unroll
            for (int u = 0; u < 16; ++u) {
                const int k = u * 16 + i;
                a += s2[k] * w1[k * CR + j];
            }
            red[tid] = a;
        }
        __syncthreads();
        if (tid < CR) {
            float acc = b1[tid];
#pragma unroll
            for (int i2 = 0; i2 < 16; ++i2) acc += red[i2 * 16 + tid];
            h[tid] = fmaxf(acc, 0.f);
        }
        __syncthreads();

        // layer 2: one channel per thread
        {
            float acc = b2[tid];
#pragma unroll
            for (int u = 0; u < CR; ++u) acc += h[u] * w2[u * C + tid];
            g[b * C + tid] = 1.f / (1.f + expf(-acc));
        }
    }

    grid_barrier(sync + 32, GRID);   // separate cacheline

    // ---------------- phase 3: scale, 2 tiles/block -------------------------
    v4f* __restrict__ ov = (v4f*)out;
#pragma unroll
    for (int rep = 0; rep < 2; ++rep) {
        const int t  = bid + rep * GRID;
        const int b  = t / SBLK;
        const int c0 = (tid & 63) * 4;   // channel group invariant per thread
        const float g0 = g[b * C + c0 + 0];
        const float g1 = g[b * C + c0 + 1];
        const float g2 = g[b * C + c0 + 2];
        const float g3 = g[b * C + c0 + 3];

        const size_t base = (size_t)t * 4096;
#pragma unroll
        for (int k = 0; k < 16; ++k) {
            const size_t p = base + tid + (size_t)k * 256;
            v4f v = xv[p];                      // LLC-hot from phase 1
            v.x *= g0; v.y *= g1; v.z *= g2; v.w *= g3;
            __builtin_nontemporal_store(v, &ov[p]);   // never re-read
        }
    }
}

extern "C" void kernel_launch(void* const* d_in, const int* in_sizes, int n_in,
                              void* d_out, int out_size, void* d_ws, size_t ws_size,
                              hipStream_t stream) {
    const float* x  = (const float*)d_in[0];
    const float* w1 = (const float*)d_in[1];
    const float* b1 = (const float*)d_in[2];
    const float* w2 = (const float*)d_in[3];
    const float* b2 = (const float*)d_in[4];
    float* out = (float*)d_out;

    float* partial = (float*)d_ws;                    // NTILE*C floats = 1.6 MB
    float* g       = partial + (size_t)NTILE * C;     // BATCH*C floats = 32 KB
    int*   sync    = (int*)(g + (size_t)BATCH * C);   // 2 counters (offset 0, 32)

    hipMemsetAsync(sync, 0, 256, stream);             // ws is poisoned 0xAA

    se_fused<<<dim3(GRID), dim3(256), 0, stream>>>(
        x, w1, b1, w2, b2, out, partial, g, sync);
}